// Round 17
// baseline (227.523 us; speedup 1.0000x reference)
//
#include <hip/hip_runtime.h>

typedef __attribute__((ext_vector_type(8))) __bf16 bf16x8;
typedef __attribute__((ext_vector_type(4))) float f32x4;
typedef __attribute__((ext_vector_type(16))) float f32x16;
typedef __attribute__((ext_vector_type(2))) int i32x2;

__device__ __forceinline__ ushort f2b(float f) {
    uint u = __builtin_bit_cast(uint, f);
    u += 0x7fffu + ((u >> 16) & 1u);
    return (ushort)(u >> 16);
}
__device__ __forceinline__ float b2f(ushort h) {
    uint u = ((uint)h) << 16;
    return __builtin_bit_cast(float, u);
}
__device__ __forceinline__ uint cvtpk(float a, float b) {
    uint r;
    asm("v_cvt_pk_bf16_f32 %0, %1, %2" : "=v"(r) : "v"(a), "v"(b));
    return r;
}

// ---------------- fused casts: key|value, wq|wk|wv, permuted w_aoa in ONE launch ----------------
// grid = 16384 (kv) + 3072 (w) + 4096 (aoa) = 23552 blocks x 256
__global__ __launch_bounds__(256) void cast_all(const float* __restrict__ key,
                                                const float* __restrict__ value,
                                                const float* __restrict__ wq,
                                                const float* __restrict__ wk,
                                                const float* __restrict__ wv,
                                                const float* __restrict__ waoa,
                                                ushort* __restrict__ keyb,
                                                ushort* __restrict__ wqb,
                                                ushort* __restrict__ wab) {
    int bid = blockIdx.x;
    int tid = threadIdx.x;
    if (bid < 16384) {
        const float* src = (bid < 8192) ? key : value;
        float4 v = *(const float4*)(src + ((size_t)(bid & 8191) * 256 + tid) * 4);
        ushort4 o;
        o.x = f2b(v.x); o.y = f2b(v.y); o.z = f2b(v.z); o.w = f2b(v.w);
        *(ushort4*)(keyb + (size_t)bid * 1024 + tid * 4) = o;
    } else if (bid < 19456) {
        int b2 = bid - 16384;
        const float* src = (b2 < 1024) ? wq : ((b2 < 2048) ? wk : wv);
        float4 v = *(const float4*)(src + ((size_t)(b2 & 1023) * 256 + tid) * 4);
        ushort4 o;
        o.x = f2b(v.x); o.y = f2b(v.y); o.z = f2b(v.z); o.w = f2b(v.w);
        *(ushort4*)(wqb + (size_t)b2 * 1024 + tid * 4) = o;
    } else {
        int b3 = bid - 19456;
        int n1 = b3 >> 1;
        int c = (b3 & 1) * 1024 + tid * 4;
        int q = ((n1 & 63) | ((n1 >> 7) << 6)) + ((n1 >> 6) & 1) * 1024;
        float4 v = *(const float4*)(waoa + (size_t)q * 2048 + c);
        ushort4 o;
        o.x = f2b(v.x); o.y = f2b(v.y); o.z = f2b(v.z); o.w = f2b(v.w);
        *(ushort4*)(wab + (size_t)n1 * 2048 + c) = o;
    }
}

// ---------------- LayerNorm(query) -> bf16 into xq[:,1024:2048] ----------------
__global__ __launch_bounds__(256) void ln_kernel(const float* __restrict__ x,
                                                 const float* __restrict__ ga,
                                                 const float* __restrict__ be,
                                                 ushort* __restrict__ xq) {
    const int row = blockIdx.x, tid = threadIdx.x;
    __shared__ float red[4];
    float4 v = ((const float4*)(x + (size_t)row * 1024))[tid];
    float sm = v.x + v.y + v.z + v.w;
    for (int off = 32; off; off >>= 1) sm += __shfl_xor(sm, off);
    if ((tid & 63) == 0) red[tid >> 6] = sm;
    __syncthreads();
    float mean = (red[0] + red[1] + red[2] + red[3]) * (1.f / 1024.f);
    __syncthreads();
    float dx = v.x - mean, dy = v.y - mean, dz = v.z - mean, dw = v.w - mean;
    float s2 = dx * dx + dy * dy + dz * dz + dw * dw;
    for (int off = 32; off; off >>= 1) s2 += __shfl_xor(s2, off);
    if ((tid & 63) == 0) red[tid >> 6] = s2;
    __syncthreads();
    float var = (red[0] + red[1] + red[2] + red[3]) * (1.f / 1023.f);
    float inv = 1.f / (sqrtf(var) + 1e-6f);
    float4 g = ((const float4*)ga)[tid];
    float4 bb = ((const float4*)be)[tid];
    ushort4 o;
    o.x = f2b(g.x * dx * inv + bb.x);
    o.y = f2b(g.y * dy * inv + bb.y);
    o.z = f2b(g.z * dz * inv + bb.z);
    o.w = f2b(g.w * dw * inv + bb.w);
    *(ushort4*)&xq[(size_t)row * 2048 + 1024 + tid * 4] = o;
}

// ---------------- GEMM v6 (AOA + fused GLU): 256x256, BK=64, deep pipeline (frozen) ----------------
template <int MODE>
__global__ __launch_bounds__(512, 2) void gemm6(const ushort* __restrict__ Aq, int ldaq,
                                                const ushort* __restrict__ B, int ldb,
                                                const float* __restrict__ bias0,
                                                void* __restrict__ out0,
                                                int K, int NB) {
    __shared__ ushort lds[2][32768];

    const int tid = threadIdx.x;
    const int w = tid >> 6, l = tid & 63;
    const int wr = w >> 2, wcn = w & 3;
    const int r16 = l & 15, g4 = l >> 4;

    const int bid = blockIdx.x;
    const int cpx = gridDim.x >> 3;
    const int swz = (bid & 7) * cpx + (bid >> 3);
    const int m0 = (swz / NB) * 256;
    const int n0 = (swz % NB) * 256;

    const ushort* A = Aq;
    const int lda = ldaq;

    const int srow8 = l >> 3;
    const int sxor8 = ((l & 7) ^ srow8) * 8;
    const ushort* As0 = A + (size_t)(m0 + w * 8 + srow8) * lda + sxor8;
    const ushort* Bs0 = B + (size_t)(n0 + w * 8 + srow8) * ldb + sxor8;

    f32x4 acc[8][4];
#pragma unroll
    for (int i = 0; i < 8; i++)
#pragma unroll
        for (int j = 0; j < 4; j++) acc[i][j] = (f32x4){0.f, 0.f, 0.f, 0.f};

    const int sw16 = (r16 & 7) << 4;
    char* ldsb = (char*)&lds[0][0];

#define STAGE_H(sel_, HS_, kt_)                                                            \
    do {                                                                                   \
        const int mat_ = (HS_)&1, half_ = (HS_) >> 1;                                      \
        const ushort* sb_ = mat_ ? Bs0 : As0;                                              \
        const int ld_ = mat_ ? ldb : lda;                                                  \
        _Pragma("unroll") for (int li_ = 0; li_ < 2; li_++) {                              \
            const ushort* src_ = sb_ + (size_t)(half_ * 128 + li_ * 64) * ld_ + (kt_)*64;  \
            int dst_ = (sel_)*65536 + mat_ * 32768 + half_ * 16384 + li_ * 8192 + w * 1024;\
            __builtin_amdgcn_global_load_lds(                                              \
                (const __attribute__((address_space(1))) void*)src_,                       \
                (__attribute__((address_space(3))) void*)(ldsb + dst_), 16, 0, 0);         \
        }                                                                                  \
    } while (0)

    auto LDA4 = [&](bf16x8 (&dst)[4][2], int sel, int half) {
#pragma unroll
        for (int ai = 0; ai < 4; ai++)
#pragma unroll
            for (int ks = 0; ks < 2; ks++)
                dst[ai][ks] = *(const bf16x8*)(ldsb + sel * 65536 + half * 16384 +
                                               (wr * 16 + 32 * ai + r16) * 128 +
                                               ((ks * 64 + g4 * 16) ^ sw16));
    };
    auto LDB2 = [&](bf16x8 (&dst)[2][2], int sel, int half) {
#pragma unroll
        for (int bi = 0; bi < 2; bi++)
#pragma unroll
            for (int ks = 0; ks < 2; ks++)
                dst[bi][ks] = *(const bf16x8*)(ldsb + sel * 65536 + 32768 + half * 16384 +
                                               (wcn * 16 + 64 * bi + r16) * 128 +
                                               ((ks * 64 + g4 * 16) ^ sw16));
    };
    auto MM = [&](bf16x8 (&af)[4][2], bf16x8 (&bf)[2][2], int A0, int B0) {
        __builtin_amdgcn_s_setprio(1);
#pragma unroll
        for (int ks = 0; ks < 2; ks++)
#pragma unroll
            for (int ai = 0; ai < 4; ai++)
#pragma unroll
                for (int bi = 0; bi < 2; bi++)
                    acc[A0 + ai][B0 + bi] = __builtin_amdgcn_mfma_f32_16x16x32_bf16(
                        af[ai][ks], bf[bi][ks], acc[A0 + ai][B0 + bi], 0, 0, 0);
        __builtin_amdgcn_s_setprio(0);
    };

    const int NT = K >> 6;

    STAGE_H(0, 0, 0); STAGE_H(0, 1, 0); STAGE_H(0, 2, 0); STAGE_H(0, 3, 0);
    STAGE_H(1, 0, 1); STAGE_H(1, 1, 1); STAGE_H(1, 2, 1);
    asm volatile("s_waitcnt vmcnt(10)" ::: "memory");
    __builtin_amdgcn_s_barrier();

    bf16x8 aL[4][2], aH[4][2], bL[2][2], bH[2][2];

    for (int t = 0; t < NT - 2; ++t) {
        const int sel = t & 1;
        LDA4(aL, sel, 0); LDB2(bL, sel, 0);
        STAGE_H(sel ^ 1, 3, t + 1);
        __builtin_amdgcn_s_barrier();
        MM(aL, bL, 0, 0);
        asm volatile("s_waitcnt vmcnt(10)" ::: "memory");
        __builtin_amdgcn_s_barrier();
        LDA4(aH, sel, 1);
        STAGE_H(sel, 0, t + 2);
        __builtin_amdgcn_s_barrier();
        MM(aH, bL, 4, 0);
        asm volatile("s_waitcnt vmcnt(10)" ::: "memory");
        __builtin_amdgcn_s_barrier();
        LDB2(bH, sel, 1);
        STAGE_H(sel, 1, t + 2);
        __builtin_amdgcn_s_barrier();
        MM(aH, bH, 4, 2);
        __builtin_amdgcn_s_barrier();
        STAGE_H(sel, 2, t + 2);
        __builtin_amdgcn_s_barrier();
        MM(aL, bH, 0, 2);
        asm volatile("s_waitcnt vmcnt(10)" ::: "memory");
        __builtin_amdgcn_s_barrier();
    }
    {
        const int sel = (NT - 2) & 1;
        LDA4(aL, sel, 0); LDB2(bL, sel, 0);
        STAGE_H(sel ^ 1, 3, NT - 1);
        __builtin_amdgcn_s_barrier();
        MM(aL, bL, 0, 0);
        asm volatile("s_waitcnt vmcnt(10)" ::: "memory");
        __builtin_amdgcn_s_barrier();
        LDA4(aH, sel, 1);
        __builtin_amdgcn_s_barrier();
        MM(aH, bL, 4, 0);
        asm volatile("s_waitcnt vmcnt(8)" ::: "memory");
        __builtin_amdgcn_s_barrier();
        LDB2(bH, sel, 1);
        __builtin_amdgcn_s_barrier();
        MM(aH, bH, 4, 2);
        __builtin_amdgcn_s_barrier();
        MM(aL, bH, 0, 2);
        asm volatile("s_waitcnt vmcnt(4)" ::: "memory");
        __builtin_amdgcn_s_barrier();
    }
    {
        const int sel = (NT - 1) & 1;
        LDA4(aL, sel, 0); LDB2(bL, sel, 0);
        __builtin_amdgcn_s_barrier();
        MM(aL, bL, 0, 0);
        asm volatile("s_waitcnt vmcnt(2)" ::: "memory");
        __builtin_amdgcn_s_barrier();
        LDA4(aH, sel, 1);
        __builtin_amdgcn_s_barrier();
        MM(aH, bL, 4, 0);
        asm volatile("s_waitcnt vmcnt(0)" ::: "memory");
        __builtin_amdgcn_s_barrier();
        LDB2(bH, sel, 1);
        MM(aH, bH, 4, 2);
        MM(aL, bH, 0, 2);
    }
#undef STAGE_H

    float* out = (float*)out0;
#pragma unroll
    for (int bp = 0; bp < 2; bp++) {
        int j = (n0 >> 1) + wcn * 16 + 64 * bp + r16;
        float bsa = bias0[j];
        float bsg = bias0[j + 1024];
#pragma unroll
        for (int a_ = 0; a_ < 8; a_++) {
            int mr = m0 + wr * 16 + 32 * a_ + g4 * 4;
#pragma unroll
            for (int r = 0; r < 4; r++) {
                float av = acc[a_][2 * bp][r] + bsa;
                float gv = acc[a_][2 * bp + 1][r] + bsg;
                out[(size_t)(mr + r) * 1024 + j] = av * (1.f / (1.f + __expf(-gv)));
            }
        }
    }
}

// ---------------- GEMM v7q (Q projection): 128x256, bf16 A via gload_lds, grid 256 (frozen) ----------------
__global__ __launch_bounds__(512, 2) void gemm7q(const ushort* __restrict__ A, int lda,
                                                 const ushort* __restrict__ B, int ldb,
                                                 const float* __restrict__ bias,
                                                 ushort* __restrict__ C, float qscale) {
    __shared__ ushort lds[2][24576];

    const int tid = threadIdx.x;
    const int w = tid >> 6, l = tid & 63;
    const int wr = w >> 2, wcn = w & 3;
    const int r16 = l & 15, g4 = l >> 4;

    const int bid = blockIdx.x;
    const int cpx = gridDim.x >> 3;
    const int swz = (bid & 7) * cpx + (bid >> 3);
    const int m0 = (swz >> 2) * 128;
    const int n0 = (swz & 3) * 256;

    const int srow8 = l >> 3;
    const int sxor8 = ((l & 7) ^ srow8) * 8;
    const ushort* As0 = A + (size_t)(m0 + w * 8 + srow8) * lda + sxor8;
    const ushort* Bs0 = B + (size_t)(n0 + w * 8 + srow8) * ldb + sxor8;

    f32x4 acc[4][4];
#pragma unroll
    for (int i = 0; i < 4; i++)
#pragma unroll
        for (int j = 0; j < 4; j++) acc[i][j] = (f32x4){0.f, 0.f, 0.f, 0.f};

    const int sw16 = (r16 & 7) << 4;
    char* ldsb = (char*)&lds[0][0];

#define STAGE_A(sel_, h_, kt_)                                                             \
    __builtin_amdgcn_global_load_lds(                                                      \
        (const __attribute__((address_space(1))) void*)(As0 + (size_t)((h_)*64) * lda + (kt_)*64), \
        (__attribute__((address_space(3))) void*)(ldsb + (sel_)*49152 + (h_)*8192 + w * 1024), 16, 0, 0)
#define STAGE_B(sel_, h_, li_, kt_)                                                        \
    __builtin_amdgcn_global_load_lds(                                                      \
        (const __attribute__((address_space(1))) void*)(Bs0 + (size_t)((h_)*128 + (li_)*64) * ldb + (kt_)*64), \
        (__attribute__((address_space(3))) void*)(ldsb + (sel_)*49152 + 16384 + (h_)*16384 + (li_)*8192 + w * 1024), 16, 0, 0)

    auto LDA2 = [&](bf16x8 (&dst)[2][2], int sel, int half) {
#pragma unroll
        for (int ai = 0; ai < 2; ai++)
#pragma unroll
            for (int ks = 0; ks < 2; ks++)
                dst[ai][ks] = *(const bf16x8*)(ldsb + sel * 49152 + half * 8192 +
                                               (wr * 16 + 32 * ai + r16) * 128 +
                                               ((ks * 64 + g4 * 16) ^ sw16));
    };
    auto LDB2 = [&](bf16x8 (&dst)[2][2], int sel, int half) {
#pragma unroll
        for (int bi = 0; bi < 2; bi++)
#pragma unroll
            for (int ks = 0; ks < 2; ks++)
                dst[bi][ks] = *(const bf16x8*)(ldsb + sel * 49152 + 16384 + half * 16384 +
                                               (wcn * 16 + 64 * bi + r16) * 128 +
                                               ((ks * 64 + g4 * 16) ^ sw16));
    };
    auto MM = [&](bf16x8 (&af)[2][2], bf16x8 (&bf)[2][2], int A0, int B0) {
        __builtin_amdgcn_s_setprio(1);
#pragma unroll
        for (int ks = 0; ks < 2; ks++)
#pragma unroll
            for (int ai = 0; ai < 2; ai++)
#pragma unroll
                for (int bi = 0; bi < 2; bi++)
                    acc[A0 + ai][B0 + bi] = __builtin_amdgcn_mfma_f32_16x16x32_bf16(
                        af[ai][ks], bf[bi][ks], acc[A0 + ai][B0 + bi], 0, 0, 0);
        __builtin_amdgcn_s_setprio(0);
    };

    const int NT = 16;

    STAGE_A(0, 0, 0); STAGE_B(0, 0, 0, 0); STAGE_B(0, 0, 1, 0);
    STAGE_A(0, 1, 0); STAGE_B(0, 1, 0, 0); STAGE_B(0, 1, 1, 0);
    STAGE_A(1, 0, 1); STAGE_B(1, 0, 0, 1); STAGE_B(1, 0, 1, 1);
    STAGE_A(1, 1, 1);
    asm volatile("s_waitcnt vmcnt(7)" ::: "memory");
    __builtin_amdgcn_s_barrier();

    bf16x8 aL[2][2], aH[2][2], bL[2][2], bH[2][2];

    for (int t = 0; t < NT - 2; ++t) {
        const int sel = t & 1;
        LDA2(aL, sel, 0); LDB2(bL, sel, 0);
        STAGE_B(sel ^ 1, 1, 0, t + 1); STAGE_B(sel ^ 1, 1, 1, t + 1);
        __builtin_amdgcn_s_barrier();
        MM(aL, bL, 0, 0);
        asm volatile("s_waitcnt vmcnt(8)" ::: "memory");
        __builtin_amdgcn_s_barrier();
        LDA2(aH, sel, 1);
        STAGE_A(sel, 0, t + 2);
        __builtin_amdgcn_s_barrier();
        MM(aH, bL, 2, 0);
        asm volatile("s_waitcnt vmcnt(7)" ::: "memory");
        __builtin_amdgcn_s_barrier();
        LDB2(bH, sel, 1);
        STAGE_B(sel, 0, 0, t + 2); STAGE_B(sel, 0, 1, t + 2);
        __builtin_amdgcn_s_barrier();
        MM(aH, bH, 2, 2);
        __builtin_amdgcn_s_barrier();
        STAGE_A(sel, 1, t + 2);
        __builtin_amdgcn_s_barrier();
        MM(aL, bH, 0, 2);
        asm volatile("s_waitcnt vmcnt(7)" ::: "memory");
        __builtin_amdgcn_s_barrier();
    }
    {
        const int sel = (NT - 2) & 1;
        LDA2(aL, sel, 0); LDB2(bL, sel, 0);
        STAGE_B(sel ^ 1, 1, 0, NT - 1); STAGE_B(sel ^ 1, 1, 1, NT - 1);
        __builtin_amdgcn_s_barrier();
        MM(aL, bL, 0, 0);
        asm volatile("s_waitcnt vmcnt(8)" ::: "memory");
        __builtin_amdgcn_s_barrier();
        LDA2(aH, sel, 1);
        __builtin_amdgcn_s_barrier();
        MM(aH, bL, 2, 0);
        asm volatile("s_waitcnt vmcnt(6)" ::: "memory");
        __builtin_amdgcn_s_barrier();
        LDB2(bH, sel, 1);
        __builtin_amdgcn_s_barrier();
        MM(aH, bH, 2, 2);
        __builtin_amdgcn_s_barrier();
        MM(aL, bH, 0, 2);
        asm volatile("s_waitcnt vmcnt(3)" ::: "memory");
        __builtin_amdgcn_s_barrier();
    }
    {
        const int sel = (NT - 1) & 1;
        LDA2(aL, sel, 0); LDB2(bL, sel, 0);
        __builtin_amdgcn_s_barrier();
        MM(aL, bL, 0, 0);
        asm volatile("s_waitcnt vmcnt(2)" ::: "memory");
        __builtin_amdgcn_s_barrier();
        LDA2(aH, sel, 1);
        __builtin_amdgcn_s_barrier();
        MM(aH, bL, 2, 0);
        asm volatile("s_waitcnt vmcnt(0)" ::: "memory");
        __builtin_amdgcn_s_barrier();
        LDB2(bH, sel, 1);
        MM(aH, bH, 2, 2);
        MM(aL, bH, 0, 2);
    }
#undef STAGE_A
#undef STAGE_B

#pragma unroll
    for (int b_ = 0; b_ < 4; b_++) {
        int n = n0 + wcn * 16 + 64 * b_ + r16;
        float bs = bias[n];
#pragma unroll
        for (int a_ = 0; a_ < 4; a_++) {
            int mr = m0 + wr * 16 + 32 * a_ + g4 * 4;
#pragma unroll
            for (int r = 0; r < 4; r++)
                C[(size_t)(mr + r) * 1024 + n] = f2b((acc[a_][b_][r] + bs) * qscale);
        }
    }
}

// ---------------- GEMM v7kv (K/V): R13-proven schedule, bf16 A via gload_lds, grid 512 ----------------
__global__ __launch_bounds__(512, 2) void gemm7kv(const ushort* __restrict__ Ak,
                                                  const ushort* __restrict__ Av,
                                                  const ushort* __restrict__ B, int ldb,
                                                  const float* __restrict__ biask,
                                                  const float* __restrict__ biasv,
                                                  ushort* __restrict__ Kb,
                                                  ushort* __restrict__ Vt) {
    __shared__ ushort lds[2][24576];

    const int tid = threadIdx.x;
    const int w = tid >> 6, l = tid & 63;
    const int wr = w >> 2, wcn = w & 3;
    const int r16 = l & 15, g4 = l >> 4;

    const int bid = blockIdx.x;               // 512
    const int cpx = gridDim.x >> 3;
    const int swz = (bid & 7) * cpx + (bid >> 3);
    const int m0 = (swz >> 3) * 128;
    const int n0 = (swz & 7) * 256;           // over wk|wv (2048 rows)
    const int kreg = n0 >> 10;                // 0 = K, 1 = V
    const ushort* A = kreg ? Av : Ak;
    const int lda = 1024;

    const int srow8 = l >> 3;
    const int sxor8 = ((l & 7) ^ srow8) * 8;
    const ushort* As0 = A + (size_t)(m0 + w * 8 + srow8) * lda + sxor8;
    const ushort* Bs0 = B + (size_t)(n0 + w * 8 + srow8) * ldb + sxor8;

    f32x4 acc[4][4];
#pragma unroll
    for (int i = 0; i < 4; i++)
#pragma unroll
        for (int j = 0; j < 4; j++) acc[i][j] = (f32x4){0.f, 0.f, 0.f, 0.f};

    const int sw16 = (r16 & 7) << 4;
    char* ldsb = (char*)&lds[0][0];

#define STAGE_A(sel_, h_, kt_)                                                             \
    __builtin_amdgcn_global_load_lds(                                                      \
        (const __attribute__((address_space(1))) void*)(As0 + (size_t)((h_)*64) * lda + (kt_)*64), \
        (__attribute__((address_space(3))) void*)(ldsb + (sel_)*49152 + (h_)*8192 + w * 1024), 16, 0, 0)
#define STAGE_B(sel_, h_, li_, kt_)                                                        \
    __builtin_amdgcn_global_load_lds(                                                      \
        (const __attribute__((address_space(1))) void*)(Bs0 + (size_t)((h_)*128 + (li_)*64) * ldb + (kt_)*64), \
        (__attribute__((address_space(3))) void*)(ldsb + (sel_)*49152 + 16384 + (h_)*16384 + (li_)*8192 + w * 1024), 16, 0, 0)

    auto LDA2 = [&](bf16x8 (&dst)[2][2], int sel, int half) {
#pragma unroll
        for (int ai = 0; ai < 2; ai++)
#pragma unroll
            for (int ks = 0; ks < 2; ks++)
                dst[ai][ks] = *(const bf16x8*)(ldsb + sel * 49152 + half * 8192 +
                                               (wr * 16 + 32 * ai + r16) * 128 +
                                               ((ks * 64 + g4 * 16) ^ sw16));
    };
    auto LDB2 = [&](bf16x8 (&dst)[2][2], int sel, int half) {
#pragma unroll
        for (int bi = 0; bi < 2; bi++)
#pragma unroll
            for (int ks = 0; ks < 2; ks++)
                dst[bi][ks] = *(const bf16x8*)(ldsb + sel * 49152 + 16384 + half * 16384 +
                                               (wcn * 16 + 64 * bi + r16) * 128 +
                                               ((ks * 64 + g4 * 16) ^ sw16));
    };
    auto MM = [&](bf16x8 (&af)[2][2], bf16x8 (&bf)[2][2], int A0, int B0) {
        __builtin_amdgcn_s_setprio(1);
#pragma unroll
        for (int ks = 0; ks < 2; ks++)
#pragma unroll
            for (int ai = 0; ai < 2; ai++)
#pragma unroll
                for (int bi = 0; bi < 2; bi++)
                    acc[A0 + ai][B0 + bi] = __builtin_amdgcn_mfma_f32_16x16x32_bf16(
                        af[ai][ks], bf[bi][ks], acc[A0 + ai][B0 + bi], 0, 0, 0);
        __builtin_amdgcn_s_setprio(0);
    };

    const int NT = 16;

    STAGE_A(0, 0, 0); STAGE_B(0, 0, 0, 0); STAGE_B(0, 0, 1, 0);
    STAGE_A(0, 1, 0); STAGE_B(0, 1, 0, 0); STAGE_B(0, 1, 1, 0);
    STAGE_A(1, 0, 1); STAGE_B(1, 0, 0, 1); STAGE_B(1, 0, 1, 1);
    STAGE_A(1, 1, 1);
    asm volatile("s_waitcnt vmcnt(7)" ::: "memory");
    __builtin_amdgcn_s_barrier();

    bf16x8 aL[2][2], aH[2][2], bL[2][2], bH[2][2];

    for (int t = 0; t < NT - 2; ++t) {
        const int sel = t & 1;
        LDA2(aL, sel, 0); LDB2(bL, sel, 0);
        STAGE_B(sel ^ 1, 1, 0, t + 1); STAGE_B(sel ^ 1, 1, 1, t + 1);
        __builtin_amdgcn_s_barrier();
        MM(aL, bL, 0, 0);
        asm volatile("s_waitcnt vmcnt(8)" ::: "memory");
        __builtin_amdgcn_s_barrier();
        LDA2(aH, sel, 1);
        STAGE_A(sel, 0, t + 2);
        __builtin_amdgcn_s_barrier();
        MM(aH, bL, 2, 0);
        asm volatile("s_waitcnt vmcnt(7)" ::: "memory");
        __builtin_amdgcn_s_barrier();
        LDB2(bH, sel, 1);
        STAGE_B(sel, 0, 0, t + 2); STAGE_B(sel, 0, 1, t + 2);
        __builtin_amdgcn_s_barrier();
        MM(aH, bH, 2, 2);
        __builtin_amdgcn_s_barrier();
        STAGE_A(sel, 1, t + 2);
        __builtin_amdgcn_s_barrier();
        MM(aL, bH, 0, 2);
        asm volatile("s_waitcnt vmcnt(7)" ::: "memory");
        __builtin_amdgcn_s_barrier();
    }
    {
        const int sel = (NT - 2) & 1;
        LDA2(aL, sel, 0); LDB2(bL, sel, 0);
        STAGE_B(sel ^ 1, 1, 0, NT - 1); STAGE_B(sel ^ 1, 1, 1, NT - 1);
        __builtin_amdgcn_s_barrier();
        MM(aL, bL, 0, 0);
        asm volatile("s_waitcnt vmcnt(8)" ::: "memory");
        __builtin_amdgcn_s_barrier();
        LDA2(aH, sel, 1);
        __builtin_amdgcn_s_barrier();
        MM(aH, bL, 2, 0);
        asm volatile("s_waitcnt vmcnt(6)" ::: "memory");
        __builtin_amdgcn_s_barrier();
        LDB2(bH, sel, 1);
        __builtin_amdgcn_s_barrier();
        MM(aH, bH, 2, 2);
        __builtin_amdgcn_s_barrier();
        MM(aL, bH, 0, 2);
        asm volatile("s_waitcnt vmcnt(3)" ::: "memory");
        __builtin_amdgcn_s_barrier();
    }
    {
        const int sel = (NT - 1) & 1;
        LDA2(aL, sel, 0); LDB2(bL, sel, 0);
        __builtin_amdgcn_s_barrier();
        MM(aL, bL, 0, 0);
        asm volatile("s_waitcnt vmcnt(2)" ::: "memory");
        __builtin_amdgcn_s_barrier();
        LDA2(aH, sel, 1);
        __builtin_amdgcn_s_barrier();
        MM(aH, bL, 2, 0);
        asm volatile("s_waitcnt vmcnt(0)" ::: "memory");
        __builtin_amdgcn_s_barrier();
        LDB2(bH, sel, 1);
        MM(aH, bH, 2, 2);
        MM(aL, bH, 0, 2);
    }
#undef STAGE_A
#undef STAGE_B

    const int nr0 = n0 & 1023;
    const float* bias = kreg ? biasv : biask;
    if (kreg == 0) {
#pragma unroll
        for (int b_ = 0; b_ < 4; b_++) {
            int n = nr0 + wcn * 16 + 64 * b_ + r16;
            float bs = bias[n];
#pragma unroll
            for (int a_ = 0; a_ < 4; a_++) {
                int mr = m0 + wr * 16 + 32 * a_ + g4 * 4;
#pragma unroll
                for (int r = 0; r < 4; r++)
                    Kb[(size_t)(mr + r) * 1024 + n] = f2b(acc[a_][b_][r] + bs);
            }
        }
    } else {
#pragma unroll
        for (int b_ = 0; b_ < 4; b_++) {
            int n = nr0 + wcn * 16 + 64 * b_ + r16;
            float bs = bias[n];
            int h = n >> 7, d = n & 127;
#pragma unroll
            for (int a_ = 0; a_ < 4; a_++) {
                int mr = m0 + wr * 16 + 32 * a_ + g4 * 4;
                int bb = mr >> 10, s_ = mr & 1023;
                ushort4 o;
                o.x = f2b(acc[a_][b_][0] + bs);
                o.y = f2b(acc[a_][b_][1] + bs);
                o.z = f2b(acc[a_][b_][2] + bs);
                o.w = f2b(acc[a_][b_][3] + bs);
                *(ushort4*)&Vt[((size_t)(bb * 8 + h) * 128 + d) * 1024 + s_] = o;
            }
        }
    }
}

// ---------------- flash attention v8 (unchanged) ----------------
__global__ __launch_bounds__(256, 2) void attn_kernel(const ushort* __restrict__ Q,
                                                      const ushort* __restrict__ Kt,
                                                      const ushort* __restrict__ Vt,
                                                      const int* __restrict__ mask,
                                                      ushort* __restrict__ xq) {
    __shared__ ushort Ks[2][8192];
    __shared__ ushort Vs[2][8192];

    const int tid = threadIdx.x;
    const int l = tid & 63, wid = tid >> 6;
    const int ql = l & 31, hi = l >> 5;
    const int id = blockIdx.x;
    const int bh = ((id >> 6) << 3) | (id & 7);
    const int qb = (id >> 3) & 7;
    const int b = bh >> 3, h = bh & 7;
    const int q0 = qb * 128 + wid * 32;

    bf16x8 qf[8];
    const ushort* Qrow = Q + (size_t)(b * 1024 + q0 + ql) * 1024 + h * 128 + hi * 8;
#pragma unroll
    for (int ks = 0; ks < 8; ks++) qf[ks] = *(const bf16x8*)(Qrow + ks * 16);

    const ushort* Kg = Kt + ((size_t)b * 1024) * 1024 + h * 128;
    const ushort* Vg = Vt + (size_t)(b * 8 + h) * 128 * 1024;
    const int* mptr = mask + b * 1024;

    f32x16 xacc[4];
#pragma unroll
    for (int i = 0; i < 4; i++)
#pragma unroll
        for (int r = 0; r < 16; r++) xacc[i][r] = 0.f;
    float mrow = -INFINITY, lrow = 0.f, sclp = 0.f;
    bool resc = true;
    bf16x8 pa[4];

    auto STAGE_K = [&](int sel, int t) {
        const int kv0 = t * 64;
#pragma unroll
        for (int it = 0; it < 4; ++it) {
            int ob = it * 4096 + wid * 1024;
            int o = ob + l * 16;
            int row = o >> 8;
            int sc = (o & 255) ^ ((row & 7) << 4);
            const ushort* src = Kg + (size_t)(kv0 + row) * 1024 + (sc >> 1);
            __builtin_amdgcn_global_load_lds((const __attribute__((address_space(1))) void*)src,
                (__attribute__((address_space(3))) void*)((char*)&Ks[sel][0] + ob), 16, 0, 0);
        }
    };
    auto STAGE_V = [&](int sel, int t) {
        const int kv0 = t * 64;
#pragma unroll
        for (int it = 0; it < 4; ++it) {
            int ob = it * 4096 + wid * 1024;
            int o = ob + l * 16;
            int d = o >> 7;
            int sc = (o & 127) ^ ((d & 7) << 4);
            const ushort* src = Vg + (size_t)d * 1024 + kv0 + (sc >> 1);
            __builtin_amdgcn_global_load_lds((const __attribute__((address_space(1))) void*)src,
                (__attribute__((address_space(3))) void*)((char*)&Vs[sel][0] + ob), 16, 0, 0);
        }
    };

    auto QK = [&](f32x16 (&s)[2], int sel, unsigned long long wt) {
        const char* Kb_ = (const char*)&Ks[sel][0];
#pragma unroll
        for (int sub = 0; sub < 2; sub++) {
            f32x16 sa, sb;
#pragma unroll
            for (int r = 0; r < 16; r++) { sa[r] = 0.f; sb[r] = 0.f; }
            const int rowk = sub * 32 + ql;
            const char* kr = Kb_ + rowk * 256;
            const int sw = (rowk & 7) << 4;
            __builtin_amdgcn_s_setprio(1);
#pragma unroll
            for (int ks = 0; ks < 4; ks++) {
                bf16x8 k0 = *(const bf16x8*)(kr + (((2 * ks) * 32 + hi * 16) ^ sw));
                bf16x8 k1 = *(const bf16x8*)(kr + (((2 * ks + 1) * 32 + hi * 16) ^ sw));
                sa = __builtin_amdgcn_mfma_f32_32x32x16_bf16(k0, qf[2 * ks], sa, 0, 0, 0);
                sb = __builtin_amdgcn_mfma_f32_32x32x16_bf16(k1, qf[2 * ks + 1], sb, 0, 0, 0);
            }
            __builtin_amdgcn_s_setprio(0);
#pragma unroll
            for (int r = 0; r < 16; r++) sa[r] += sb[r];
#pragma unroll
            for (int q2 = 0; q2 < 4; q2++) {
                uint nib = (uint)(wt >> (8 * q2 + 4 * hi + 32 * sub)) & 15u;
#pragma unroll
                for (int r = 0; r < 4; r++)
                    if (!((nib >> r) & 1u)) sa[4 * q2 + r] = -1e9f;
            }
            s[sub] = sa;
        }
    };
    auto PV = [&](int sel) {
        const char* Vb_ = (const char*)&Vs[sel][0];
        if (resc) {
#pragma unroll
            for (int df = 0; df < 4; df++)
#pragma unroll
                for (int r = 0; r < 16; r++) xacc[df][r] *= sclp;
        }
        __builtin_amdgcn_s_setprio(1);
#pragma unroll
        for (int ks2 = 0; ks2 < 4; ks2++) {
#pragma unroll
            for (int df = 0; df < 4; df++) {
                const int d = df * 32 + ql;
                bf16x8 vfr = *(const bf16x8*)(Vb_ + d * 128 + ((ks2 * 32 + hi * 16) ^ ((d & 7) << 4)));
                xacc[df] = __builtin_amdgcn_mfma_f32_32x32x16_bf16(vfr, pa[ks2], xacc[df], 0, 0, 0);
            }
        }
        __builtin_amdgcn_s_setprio(0);
    };
    auto SOFTMAX = [&](f32x16 (&s)[2]) {
        float v[16];
#pragma unroll
        for (int r = 0; r < 16; r++) v[r] = fmaxf(s[0][r], s[1][r]);
#pragma unroll
        for (int st = 8; st; st >>= 1)
#pragma unroll
            for (int i = 0; i < 8; i++)
                if (i < st) v[i] = fmaxf(v[i], v[i + st]);
        float pmax = fmaxf(v[0], __shfl_xor(v[0], 32));
        if (!__all(pmax - mrow <= 8.f)) {
            float mn = fmaxf(mrow, pmax);
            sclp = __expf(mrow - mn);
            mrow = mn;
            resc = true;
        } else {
            resc = false;
        }
        float rsum = 0.f;
#pragma unroll
        for (int res = 0; res < 2; res++)
#pragma unroll
            for (int r = 0; r < 16; r++) {
                float p = __expf(s[res][r] - mrow);
                s[res][r] = p;
                rsum += p;
            }
        rsum += __shfl_xor(rsum, 32);
        lrow = (resc ? lrow * sclp : lrow) + rsum;
#pragma unroll
        for (int sub = 0; sub < 2; sub++)
#pragma unroll
            for (int g = 0; g < 2; g++) {
                const int b0 = g * 8;
                uint lo01 = cvtpk(s[sub][b0 + 0], s[sub][b0 + 1]);
                uint lo23 = cvtpk(s[sub][b0 + 2], s[sub][b0 + 3]);
                uint hi01 = cvtpk(s[sub][b0 + 4], s[sub][b0 + 5]);
                uint hi23 = cvtpk(s[sub][b0 + 6], s[sub][b0 + 7]);
                i32x2 r02 = __builtin_amdgcn_permlane32_swap((int)lo01, (int)hi01, false, false);
                i32x2 r13 = __builtin_amdgcn_permlane32_swap((int)lo23, (int)hi23, false, false);
                union { bf16x8 vv; uint u[4]; } pk;
                pk.u[0] = (uint)r02.x;
                pk.u[1] = (uint)r13.x;
                pk.u[2] = (uint)r02.y;
                pk.u[3] = (uint)r13.y;
                pa[sub * 2 + g] = pk.vv;
            }
    };

    STAGE_K(0, 0);
    int mv = mptr[l];
    asm volatile("s_waitcnt vmcnt(0)" ::: "memory");
    __syncthreads();
    STAGE_K(1, 1);
    STAGE_V(0, 0);
    unsigned long long wt = __ballot(mv != 0);
    mv = mptr[64 + l];
    f32x16 s[2];
    QK(s, 0, wt);
    SOFTMAX(s);
    int kc = 1, vc = 0;

    for (int u = 1; u < 16; ++u) {
        wt = __ballot(mv != 0);
        asm volatile("s_waitcnt vmcnt(0)" ::: "memory");
        __syncthreads();
        if (u < 15) STAGE_K(kc ^ 1, u + 1);
        STAGE_V(vc ^ 1, u);
        if (u < 15) mv = mptr[(u + 1) * 64 + l];

        QK(s, kc, wt);
        PV(vc);
        SOFTMAX(s);

        kc ^= 1; vc ^= 1;
    }

    asm volatile("s_waitcnt vmcnt(0)" ::: "memory");
    __syncthreads();
    PV(vc);

    const float inv = 1.f / lrow;
    const size_t orow = (size_t)(b * 1024 + q0 + ql) * 2048 + h * 128;
#pragma unroll
    for (int df = 0; df < 4; df++) {
#pragma unroll
        for (int q2 = 0; q2 < 4; q2++) {
            ushort4 o;
            o.x = f2b(xacc[df][4 * q2 + 0] * inv);
            o.y = f2b(xacc[df][4 * q2 + 1] * inv);
            o.z = f2b(xacc[df][4 * q2 + 2] * inv);
            o.w = f2b(xacc[df][4 * q2 + 3] * inv);
            *(ushort4*)&xq[orow + df * 32 + 8 * q2 + 4 * hi] = o;
        }
    }
}

extern "C" void kernel_launch(void* const* d_in, const int* in_sizes, int n_in,
                              void* d_out, int out_size, void* d_ws, size_t ws_size,
                              hipStream_t stream) {
    const float* query = (const float*)d_in[0];
    const float* value = (const float*)d_in[1];
    const float* key   = (const float*)d_in[2];
    const int*   mask  = (const int*)d_in[3];
    const float* ln_a  = (const float*)d_in[4];
    const float* ln_b  = (const float*)d_in[5];
    const float* wq    = (const float*)d_in[6];
    const float* bq    = (const float*)d_in[7];
    const float* wk    = (const float*)d_in[8];
    const float* bk    = (const float*)d_in[9];
    const float* wv    = (const float*)d_in[10];
    const float* bv    = (const float*)d_in[11];
    const float* waoa  = (const float*)d_in[12];
    const float* baoa  = (const float*)d_in[13];
    float* out = (float*)d_out;

    char* w8 = (char*)d_ws;
    ushort* xq   = (ushort*)(w8);                 // 8192x2048 bf16 ([x | q_ln])
    ushort* Qb   = (ushort*)(w8 + 33554432);      // 8192x1024 bf16
    ushort* Kb   = (ushort*)(w8 + 50331648);      // 8192x1024 bf16
    ushort* Vt   = (ushort*)(w8 + 67108864);      // (B,H,128,S) bf16
    ushort* keyb = (ushort*)(w8 + 83886080);      // keyb|valb contiguous bf16
    ushort* wqb  = (ushort*)(w8 + 117440512);     // 3x 1024x1024 bf16 contiguous (wq|wk|wv)
    ushort* wab  = (ushort*)(w8 + 123731968);     // 2048x2048 bf16 (PERMUTED)

    cast_all<<<23552, 256, 0, stream>>>(key, value, wq, wk, wv, waoa, keyb, wqb, wab);
    ln_kernel<<<8192, 256, 0, stream>>>(query, ln_a, ln_b, xq);

    const float qscale = 0.08838834764831845f; // 1/sqrt(128)
    ushort* valb = keyb + 8388608;

    // Q projection: 256 blocks = 1 round
    gemm7q<<<256, 512, 0, stream>>>(xq + 1024, 2048, wqb, 1024, bq, Qb, qscale);
    // K/V projections (bf16 A, R13-proven schedule): 512 blocks = 2 rounds
    gemm7kv<<<512, 512, 0, stream>>>(keyb, valb, wqb + 1048576, 1024, bk, bv, Kb, Vt);

    attn_kernel<<<512, 256, 0, stream>>>(Qb, Kb, Vt, mask, xq);

    gemm6<1><<<256, 512, 0, stream>>>(xq, 2048, wab, 2048, baoa, out, 2048, 8);
}

// Round 18
// 215.539 us; speedup vs baseline: 1.0556x; 1.0556x over previous
//
#include <hip/hip_runtime.h>

typedef __attribute__((ext_vector_type(8))) __bf16 bf16x8;
typedef __attribute__((ext_vector_type(4))) float f32x4;
typedef __attribute__((ext_vector_type(16))) float f32x16;
typedef __attribute__((ext_vector_type(2))) int i32x2;

__device__ __forceinline__ ushort f2b(float f) {
    uint u = __builtin_bit_cast(uint, f);
    u += 0x7fffu + ((u >> 16) & 1u);
    return (ushort)(u >> 16);
}
__device__ __forceinline__ float b2f(ushort h) {
    uint u = ((uint)h) << 16;
    return __builtin_bit_cast(float, u);
}
__device__ __forceinline__ uint cvtpk(float a, float b) {
    uint r;
    asm("v_cvt_pk_bf16_f32 %0, %1, %2" : "=v"(r) : "v"(a), "v"(b));
    return r;
}

// ---------------- fused casts: wq|wk|wv + permuted w_aoa ----------------
__global__ __launch_bounds__(256) void cast_all(const float* __restrict__ wq,
                                                const float* __restrict__ wk,
                                                const float* __restrict__ wv,
                                                const float* __restrict__ waoa,
                                                ushort* __restrict__ wqb,
                                                ushort* __restrict__ wab) {
    int bid = blockIdx.x;
    int tid = threadIdx.x;
    if (bid < 3072) {
        const float* src = (bid < 1024) ? wq : ((bid < 2048) ? wk : wv);
        float4 v = *(const float4*)(src + ((size_t)(bid & 1023) * 256 + tid) * 4);
        ushort4 o;
        o.x = f2b(v.x); o.y = f2b(v.y); o.z = f2b(v.z); o.w = f2b(v.w);
        *(ushort4*)(wqb + (size_t)bid * 1024 + tid * 4) = o;
    } else {
        int b3 = bid - 3072;
        int n1 = b3 >> 1;
        int c = (b3 & 1) * 1024 + tid * 4;
        int q = ((n1 & 63) | ((n1 >> 7) << 6)) + ((n1 >> 6) & 1) * 1024;
        float4 v = *(const float4*)(waoa + (size_t)q * 2048 + c);
        ushort4 o;
        o.x = f2b(v.x); o.y = f2b(v.y); o.z = f2b(v.z); o.w = f2b(v.w);
        *(ushort4*)(wab + (size_t)n1 * 2048 + c) = o;
    }
}

// ---------------- LayerNorm(query) -> bf16 into xq[:,1024:2048] ----------------
__global__ __launch_bounds__(256) void ln_kernel(const float* __restrict__ x,
                                                 const float* __restrict__ ga,
                                                 const float* __restrict__ be,
                                                 ushort* __restrict__ xq) {
    const int row = blockIdx.x, tid = threadIdx.x;
    __shared__ float red[4];
    float4 v = ((const float4*)(x + (size_t)row * 1024))[tid];
    float sm = v.x + v.y + v.z + v.w;
    for (int off = 32; off; off >>= 1) sm += __shfl_xor(sm, off);
    if ((tid & 63) == 0) red[tid >> 6] = sm;
    __syncthreads();
    float mean = (red[0] + red[1] + red[2] + red[3]) * (1.f / 1024.f);
    __syncthreads();
    float dx = v.x - mean, dy = v.y - mean, dz = v.z - mean, dw = v.w - mean;
    float s2 = dx * dx + dy * dy + dz * dz + dw * dw;
    for (int off = 32; off; off >>= 1) s2 += __shfl_xor(s2, off);
    if ((tid & 63) == 0) red[tid >> 6] = s2;
    __syncthreads();
    float var = (red[0] + red[1] + red[2] + red[3]) * (1.f / 1023.f);
    float inv = 1.f / (sqrtf(var) + 1e-6f);
    float4 g = ((const float4*)ga)[tid];
    float4 bb = ((const float4*)be)[tid];
    ushort4 o;
    o.x = f2b(g.x * dx * inv + bb.x);
    o.y = f2b(g.y * dy * inv + bb.y);
    o.z = f2b(g.z * dz * inv + bb.z);
    o.w = f2b(g.w * dw * inv + bb.w);
    *(ushort4*)&xq[(size_t)row * 2048 + 1024 + tid * 4] = o;
}

// ---------------- GEMM v6 (AOA + fused GLU): 256x256, BK=64, deep pipeline (frozen) ----------------
template <int MODE>
__global__ __launch_bounds__(512, 2) void gemm6(const ushort* __restrict__ Aq, int ldaq,
                                                const ushort* __restrict__ B, int ldb,
                                                const float* __restrict__ bias0,
                                                void* __restrict__ out0,
                                                int K, int NB) {
    __shared__ ushort lds[2][32768];

    const int tid = threadIdx.x;
    const int w = tid >> 6, l = tid & 63;
    const int wr = w >> 2, wcn = w & 3;
    const int r16 = l & 15, g4 = l >> 4;

    const int bid = blockIdx.x;
    const int cpx = gridDim.x >> 3;
    const int swz = (bid & 7) * cpx + (bid >> 3);
    const int m0 = (swz / NB) * 256;
    const int n0 = (swz % NB) * 256;

    const ushort* A = Aq;
    const int lda = ldaq;

    const int srow8 = l >> 3;
    const int sxor8 = ((l & 7) ^ srow8) * 8;
    const ushort* As0 = A + (size_t)(m0 + w * 8 + srow8) * lda + sxor8;
    const ushort* Bs0 = B + (size_t)(n0 + w * 8 + srow8) * ldb + sxor8;

    f32x4 acc[8][4];
#pragma unroll
    for (int i = 0; i < 8; i++)
#pragma unroll
        for (int j = 0; j < 4; j++) acc[i][j] = (f32x4){0.f, 0.f, 0.f, 0.f};

    const int sw16 = (r16 & 7) << 4;
    char* ldsb = (char*)&lds[0][0];

#define STAGE_H(sel_, HS_, kt_)                                                            \
    do {                                                                                   \
        const int mat_ = (HS_)&1, half_ = (HS_) >> 1;                                      \
        const ushort* sb_ = mat_ ? Bs0 : As0;                                              \
        const int ld_ = mat_ ? ldb : lda;                                                  \
        _Pragma("unroll") for (int li_ = 0; li_ < 2; li_++) {                              \
            const ushort* src_ = sb_ + (size_t)(half_ * 128 + li_ * 64) * ld_ + (kt_)*64;  \
            int dst_ = (sel_)*65536 + mat_ * 32768 + half_ * 16384 + li_ * 8192 + w * 1024;\
            __builtin_amdgcn_global_load_lds(                                              \
                (const __attribute__((address_space(1))) void*)src_,                       \
                (__attribute__((address_space(3))) void*)(ldsb + dst_), 16, 0, 0);         \
        }                                                                                  \
    } while (0)

    auto LDA4 = [&](bf16x8 (&dst)[4][2], int sel, int half) {
#pragma unroll
        for (int ai = 0; ai < 4; ai++)
#pragma unroll
            for (int ks = 0; ks < 2; ks++)
                dst[ai][ks] = *(const bf16x8*)(ldsb + sel * 65536 + half * 16384 +
                                               (wr * 16 + 32 * ai + r16) * 128 +
                                               ((ks * 64 + g4 * 16) ^ sw16));
    };
    auto LDB2 = [&](bf16x8 (&dst)[2][2], int sel, int half) {
#pragma unroll
        for (int bi = 0; bi < 2; bi++)
#pragma unroll
            for (int ks = 0; ks < 2; ks++)
                dst[bi][ks] = *(const bf16x8*)(ldsb + sel * 65536 + 32768 + half * 16384 +
                                               (wcn * 16 + 64 * bi + r16) * 128 +
                                               ((ks * 64 + g4 * 16) ^ sw16));
    };
    auto MM = [&](bf16x8 (&af)[4][2], bf16x8 (&bf)[2][2], int A0, int B0) {
        __builtin_amdgcn_s_setprio(1);
#pragma unroll
        for (int ks = 0; ks < 2; ks++)
#pragma unroll
            for (int ai = 0; ai < 4; ai++)
#pragma unroll
                for (int bi = 0; bi < 2; bi++)
                    acc[A0 + ai][B0 + bi] = __builtin_amdgcn_mfma_f32_16x16x32_bf16(
                        af[ai][ks], bf[bi][ks], acc[A0 + ai][B0 + bi], 0, 0, 0);
        __builtin_amdgcn_s_setprio(0);
    };

    const int NT = K >> 6;

    STAGE_H(0, 0, 0); STAGE_H(0, 1, 0); STAGE_H(0, 2, 0); STAGE_H(0, 3, 0);
    STAGE_H(1, 0, 1); STAGE_H(1, 1, 1); STAGE_H(1, 2, 1);
    asm volatile("s_waitcnt vmcnt(10)" ::: "memory");
    __builtin_amdgcn_s_barrier();

    bf16x8 aL[4][2], aH[4][2], bL[2][2], bH[2][2];

    for (int t = 0; t < NT - 2; ++t) {
        const int sel = t & 1;
        LDA4(aL, sel, 0); LDB2(bL, sel, 0);
        STAGE_H(sel ^ 1, 3, t + 1);
        __builtin_amdgcn_s_barrier();
        MM(aL, bL, 0, 0);
        asm volatile("s_waitcnt vmcnt(10)" ::: "memory");
        __builtin_amdgcn_s_barrier();
        LDA4(aH, sel, 1);
        STAGE_H(sel, 0, t + 2);
        __builtin_amdgcn_s_barrier();
        MM(aH, bL, 4, 0);
        asm volatile("s_waitcnt vmcnt(10)" ::: "memory");
        __builtin_amdgcn_s_barrier();
        LDB2(bH, sel, 1);
        STAGE_H(sel, 1, t + 2);
        __builtin_amdgcn_s_barrier();
        MM(aH, bH, 4, 2);
        __builtin_amdgcn_s_barrier();
        STAGE_H(sel, 2, t + 2);
        __builtin_amdgcn_s_barrier();
        MM(aL, bH, 0, 2);
        asm volatile("s_waitcnt vmcnt(10)" ::: "memory");
        __builtin_amdgcn_s_barrier();
    }
    {
        const int sel = (NT - 2) & 1;
        LDA4(aL, sel, 0); LDB2(bL, sel, 0);
        STAGE_H(sel ^ 1, 3, NT - 1);
        __builtin_amdgcn_s_barrier();
        MM(aL, bL, 0, 0);
        asm volatile("s_waitcnt vmcnt(10)" ::: "memory");
        __builtin_amdgcn_s_barrier();
        LDA4(aH, sel, 1);
        __builtin_amdgcn_s_barrier();
        MM(aH, bL, 4, 0);
        asm volatile("s_waitcnt vmcnt(8)" ::: "memory");
        __builtin_amdgcn_s_barrier();
        LDB2(bH, sel, 1);
        __builtin_amdgcn_s_barrier();
        MM(aH, bH, 4, 2);
        __builtin_amdgcn_s_barrier();
        MM(aL, bH, 0, 2);
        asm volatile("s_waitcnt vmcnt(4)" ::: "memory");
        __builtin_amdgcn_s_barrier();
    }
    {
        const int sel = (NT - 1) & 1;
        LDA4(aL, sel, 0); LDB2(bL, sel, 0);
        __builtin_amdgcn_s_barrier();
        MM(aL, bL, 0, 0);
        asm volatile("s_waitcnt vmcnt(2)" ::: "memory");
        __builtin_amdgcn_s_barrier();
        LDA4(aH, sel, 1);
        __builtin_amdgcn_s_barrier();
        MM(aH, bL, 4, 0);
        asm volatile("s_waitcnt vmcnt(0)" ::: "memory");
        __builtin_amdgcn_s_barrier();
        LDB2(bH, sel, 1);
        MM(aH, bH, 4, 2);
        MM(aL, bH, 0, 2);
    }
#undef STAGE_H

    float* out = (float*)out0;
#pragma unroll
    for (int bp = 0; bp < 2; bp++) {
        int j = (n0 >> 1) + wcn * 16 + 64 * bp + r16;
        float bsa = bias0[j];
        float bsg = bias0[j + 1024];
#pragma unroll
        for (int a_ = 0; a_ < 8; a_++) {
            int mr = m0 + wr * 16 + 32 * a_ + g4 * 4;
#pragma unroll
            for (int r = 0; r < 4; r++) {
                float av = acc[a_][2 * bp][r] + bsa;
                float gv = acc[a_][2 * bp + 1][r] + bsg;
                out[(size_t)(mr + r) * 1024 + j] = av * (1.f / (1.f + __expf(-gv)));
            }
        }
    }
}

// ---------------- GEMM v7q (Q projection only): 128x256, bf16 A via gload_lds, grid 256 ----------------
__global__ __launch_bounds__(512, 2) void gemm7q(const ushort* __restrict__ A, int lda,
                                                 const ushort* __restrict__ B, int ldb,
                                                 const float* __restrict__ bias,
                                                 ushort* __restrict__ C, float qscale) {
    __shared__ ushort lds[2][24576];

    const int tid = threadIdx.x;
    const int w = tid >> 6, l = tid & 63;
    const int wr = w >> 2, wcn = w & 3;
    const int r16 = l & 15, g4 = l >> 4;

    const int bid = blockIdx.x;
    const int cpx = gridDim.x >> 3;
    const int swz = (bid & 7) * cpx + (bid >> 3);
    const int m0 = (swz >> 2) * 128;
    const int n0 = (swz & 3) * 256;

    const int srow8 = l >> 3;
    const int sxor8 = ((l & 7) ^ srow8) * 8;
    const ushort* As0 = A + (size_t)(m0 + w * 8 + srow8) * lda + sxor8;
    const ushort* Bs0 = B + (size_t)(n0 + w * 8 + srow8) * ldb + sxor8;

    f32x4 acc[4][4];
#pragma unroll
    for (int i = 0; i < 4; i++)
#pragma unroll
        for (int j = 0; j < 4; j++) acc[i][j] = (f32x4){0.f, 0.f, 0.f, 0.f};

    const int sw16 = (r16 & 7) << 4;
    char* ldsb = (char*)&lds[0][0];

#define STAGE_A(sel_, h_, kt_)                                                             \
    __builtin_amdgcn_global_load_lds(                                                      \
        (const __attribute__((address_space(1))) void*)(As0 + (size_t)((h_)*64) * lda + (kt_)*64), \
        (__attribute__((address_space(3))) void*)(ldsb + (sel_)*49152 + (h_)*8192 + w * 1024), 16, 0, 0)
#define STAGE_B(sel_, h_, li_, kt_)                                                        \
    __builtin_amdgcn_global_load_lds(                                                      \
        (const __attribute__((address_space(1))) void*)(Bs0 + (size_t)((h_)*128 + (li_)*64) * ldb + (kt_)*64), \
        (__attribute__((address_space(3))) void*)(ldsb + (sel_)*49152 + 16384 + (h_)*16384 + (li_)*8192 + w * 1024), 16, 0, 0)

    auto LDA2 = [&](bf16x8 (&dst)[2][2], int sel, int half) {
#pragma unroll
        for (int ai = 0; ai < 2; ai++)
#pragma unroll
            for (int ks = 0; ks < 2; ks++)
                dst[ai][ks] = *(const bf16x8*)(ldsb + sel * 49152 + half * 8192 +
                                               (wr * 16 + 32 * ai + r16) * 128 +
                                               ((ks * 64 + g4 * 16) ^ sw16));
    };
    auto LDB2 = [&](bf16x8 (&dst)[2][2], int sel, int half) {
#pragma unroll
        for (int bi = 0; bi < 2; bi++)
#pragma unroll
            for (int ks = 0; ks < 2; ks++)
                dst[bi][ks] = *(const bf16x8*)(ldsb + sel * 49152 + 16384 + half * 16384 +
                                               (wcn * 16 + 64 * bi + r16) * 128 +
                                               ((ks * 64 + g4 * 16) ^ sw16));
    };
    auto MM = [&](bf16x8 (&af)[2][2], bf16x8 (&bf)[2][2], int A0, int B0) {
        __builtin_amdgcn_s_setprio(1);
#pragma unroll
        for (int ks = 0; ks < 2; ks++)
#pragma unroll
            for (int ai = 0; ai < 2; ai++)
#pragma unroll
                for (int bi = 0; bi < 2; bi++)
                    acc[A0 + ai][B0 + bi] = __builtin_amdgcn_mfma_f32_16x16x32_bf16(
                        af[ai][ks], bf[bi][ks], acc[A0 + ai][B0 + bi], 0, 0, 0);
        __builtin_amdgcn_s_setprio(0);
    };

    const int NT = 16;

    STAGE_A(0, 0, 0); STAGE_B(0, 0, 0, 0); STAGE_B(0, 0, 1, 0);
    STAGE_A(0, 1, 0); STAGE_B(0, 1, 0, 0); STAGE_B(0, 1, 1, 0);
    STAGE_A(1, 0, 1); STAGE_B(1, 0, 0, 1); STAGE_B(1, 0, 1, 1);
    STAGE_A(1, 1, 1);
    asm volatile("s_waitcnt vmcnt(7)" ::: "memory");
    __builtin_amdgcn_s_barrier();

    bf16x8 aL[2][2], aH[2][2], bL[2][2], bH[2][2];

    for (int t = 0; t < NT - 2; ++t) {
        const int sel = t & 1;
        LDA2(aL, sel, 0); LDB2(bL, sel, 0);
        STAGE_B(sel ^ 1, 1, 0, t + 1); STAGE_B(sel ^ 1, 1, 1, t + 1);
        __builtin_amdgcn_s_barrier();
        MM(aL, bL, 0, 0);
        asm volatile("s_waitcnt vmcnt(8)" ::: "memory");
        __builtin_amdgcn_s_barrier();
        LDA2(aH, sel, 1);
        STAGE_A(sel, 0, t + 2);
        __builtin_amdgcn_s_barrier();
        MM(aH, bL, 2, 0);
        asm volatile("s_waitcnt vmcnt(7)" ::: "memory");
        __builtin_amdgcn_s_barrier();
        LDB2(bH, sel, 1);
        STAGE_B(sel, 0, 0, t + 2); STAGE_B(sel, 0, 1, t + 2);
        __builtin_amdgcn_s_barrier();
        MM(aH, bH, 2, 2);
        __builtin_amdgcn_s_barrier();
        STAGE_A(sel, 1, t + 2);
        __builtin_amdgcn_s_barrier();
        MM(aL, bH, 0, 2);
        asm volatile("s_waitcnt vmcnt(7)" ::: "memory");
        __builtin_amdgcn_s_barrier();
    }
    {
        const int sel = (NT - 2) & 1;
        LDA2(aL, sel, 0); LDB2(bL, sel, 0);
        STAGE_B(sel ^ 1, 1, 0, NT - 1); STAGE_B(sel ^ 1, 1, 1, NT - 1);
        __builtin_amdgcn_s_barrier();
        MM(aL, bL, 0, 0);
        asm volatile("s_waitcnt vmcnt(8)" ::: "memory");
        __builtin_amdgcn_s_barrier();
        LDA2(aH, sel, 1);
        __builtin_amdgcn_s_barrier();
        MM(aH, bL, 2, 0);
        asm volatile("s_waitcnt vmcnt(6)" ::: "memory");
        __builtin_amdgcn_s_barrier();
        LDB2(bH, sel, 1);
        __builtin_amdgcn_s_barrier();
        MM(aH, bH, 2, 2);
        __builtin_amdgcn_s_barrier();
        MM(aL, bH, 0, 2);
        asm volatile("s_waitcnt vmcnt(3)" ::: "memory");
        __builtin_amdgcn_s_barrier();
    }
    {
        const int sel = (NT - 1) & 1;
        LDA2(aL, sel, 0); LDB2(bL, sel, 0);
        __builtin_amdgcn_s_barrier();
        MM(aL, bL, 0, 0);
        asm volatile("s_waitcnt vmcnt(2)" ::: "memory");
        __builtin_amdgcn_s_barrier();
        LDA2(aH, sel, 1);
        __builtin_amdgcn_s_barrier();
        MM(aH, bL, 2, 0);
        asm volatile("s_waitcnt vmcnt(0)" ::: "memory");
        __builtin_amdgcn_s_barrier();
        LDB2(bH, sel, 1);
        MM(aH, bH, 2, 2);
        MM(aL, bH, 0, 2);
    }
#undef STAGE_A
#undef STAGE_B

#pragma unroll
    for (int b_ = 0; b_ < 4; b_++) {
        int n = n0 + wcn * 16 + 64 * b_ + r16;
        float bs = bias[n];
#pragma unroll
        for (int a_ = 0; a_ < 4; a_++) {
            int mr = m0 + wr * 16 + 32 * a_ + g4 * 4;
#pragma unroll
            for (int r = 0; r < 4; r++)
                C[(size_t)(mr + r) * 1024 + n] = f2b((acc[a_][b_][r] + bs) * qscale);
        }
    }
}

// ---------------- GEMM v7kv (K/V projections): A read DIRECTLY from f32, reg-staged ----------------
// sched_barrier(0) after each vmcnt that guards inline-asm load results (rule #18).
__global__ __launch_bounds__(512, 2) void gemm7kv(const float* __restrict__ Akf,
                                                  const float* __restrict__ Avf,
                                                  const ushort* __restrict__ B, int ldb,
                                                  const float* __restrict__ biask,
                                                  const float* __restrict__ biasv,
                                                  ushort* __restrict__ Kb,
                                                  ushort* __restrict__ Vt) {
    __shared__ ushort lds[2][24576];   // per buf 48KB: A 128x64 (16KB) | B 256x64 (32KB)

    const int tid = threadIdx.x;
    const int w = tid >> 6, l = tid & 63;
    const int wr = w >> 2, wcn = w & 3;
    const int r16 = l & 15, g4 = l >> 4;

    const int bid = blockIdx.x;               // 512
    const int cpx = gridDim.x >> 3;
    const int swz = (bid & 7) * cpx + (bid >> 3);
    const int m0 = (swz >> 3) * 128;
    const int n0 = (swz & 7) * 256;           // 0..2047 over K|V
    const int kreg = n0 >> 10;                // 0 = K, 1 = V
    const float* Af = kreg ? Avf : Akf;

    const int srow8 = l >> 3;
    const int sxor8 = ((l & 7) ^ srow8) * 8;
    const ushort* Bs0 = B + (size_t)(n0 + w * 8 + srow8) * ldb + sxor8;

    const int arow = w * 8 + srow8;           // 0..63 within a 64-row half
    const float* As0 = Af + (size_t)(m0 + arow) * 1024 + (l & 7) * 8;
    const int awr = arow * 128 + (((l & 7) * 16) ^ ((arow & 7) << 4));  // swizzled LDS byte

    f32x4 acc[4][4];
#pragma unroll
    for (int i = 0; i < 4; i++)
#pragma unroll
        for (int j = 0; j < 4; j++) acc[i][j] = (f32x4){0.f, 0.f, 0.f, 0.f};

    const int sw16 = (r16 & 7) << 4;
    char* ldsb = (char*)&lds[0][0];

#define STAGE_B(sel_, h_, li_, kt_)                                                        \
    __builtin_amdgcn_global_load_lds(                                                      \
        (const __attribute__((address_space(1))) void*)(Bs0 + (size_t)((h_)*128 + (li_)*64) * ldb + (kt_)*64), \
        (__attribute__((address_space(3))) void*)(ldsb + (sel_)*49152 + 16384 + (h_)*16384 + (li_)*8192 + w * 1024), 16, 0, 0)

    float4 ah[2][2];
    auto GL4 = [&](float4& d, const float* p) {
        asm volatile("global_load_dwordx4 %0, %1, off" : "=&v"(d) : "v"(p) : "memory");
    };
    auto LOAD_A = [&](int kt) {   // 4 vmem loads (no auto-wait!)
#pragma unroll
        for (int h = 0; h < 2; h++) {
            const float* p = As0 + (size_t)h * 64 * 1024 + kt * 64;
            GL4(ah[h][0], p);
            GL4(ah[h][1], p + 4);
        }
    };
    auto WRITE_A = [&](int sel) {  // caller must have fenced: vmcnt + sched_barrier(0)
#pragma unroll
        for (int h = 0; h < 2; h++) {
            union { bf16x8 v; uint u[4]; } pk;
            pk.u[0] = cvtpk(ah[h][0].x, ah[h][0].y);
            pk.u[1] = cvtpk(ah[h][0].z, ah[h][0].w);
            pk.u[2] = cvtpk(ah[h][1].x, ah[h][1].y);
            pk.u[3] = cvtpk(ah[h][1].z, ah[h][1].w);
            *(bf16x8*)(ldsb + sel * 49152 + h * 8192 + awr) = pk.v;
        }
    };

    auto LDA2 = [&](bf16x8 (&dst)[2][2], int sel, int half) {
#pragma unroll
        for (int ai = 0; ai < 2; ai++)
#pragma unroll
            for (int ks = 0; ks < 2; ks++)
                dst[ai][ks] = *(const bf16x8*)(ldsb + sel * 49152 + half * 8192 +
                                               (wr * 16 + 32 * ai + r16) * 128 +
                                               ((ks * 64 + g4 * 16) ^ sw16));
    };
    auto LDB2 = [&](bf16x8 (&dst)[2][2], int sel, int half) {
#pragma unroll
        for (int bi = 0; bi < 2; bi++)
#pragma unroll
            for (int ks = 0; ks < 2; ks++)
                dst[bi][ks] = *(const bf16x8*)(ldsb + sel * 49152 + 16384 + half * 16384 +
                                               (wcn * 16 + 64 * bi + r16) * 128 +
                                               ((ks * 64 + g4 * 16) ^ sw16));
    };
    auto MM = [&](bf16x8 (&af)[2][2], bf16x8 (&bf)[2][2], int A0, int B0) {
        __builtin_amdgcn_s_setprio(1);
#pragma unroll
        for (int ks = 0; ks < 2; ks++)
#pragma unroll
            for (int ai = 0; ai < 2; ai++)
#pragma unroll
                for (int bi = 0; bi < 2; bi++)
                    acc[A0 + ai][B0 + bi] = __builtin_amdgcn_mfma_f32_16x16x32_bf16(
                        af[ai][ks], bf[bi][ks], acc[A0 + ai][B0 + bi], 0, 0, 0);
        __builtin_amdgcn_s_setprio(0);
    };

    const int NT = 16;

    // prologue: BL(0) 2; Af32(0) 4; BH(0) 2 -> vmcnt(2) retires Af32(0)+BL(0) -> write A(0)
    STAGE_B(0, 0, 0, 0); STAGE_B(0, 0, 1, 0);
    LOAD_A(0);
    STAGE_B(0, 1, 0, 0); STAGE_B(0, 1, 1, 0);
    asm volatile("s_waitcnt vmcnt(2)" ::: "memory");
    __builtin_amdgcn_sched_barrier(0);     // FENCE: keep cvt_pk below the waitcnt
    WRITE_A(0);
    asm volatile("s_waitcnt lgkmcnt(0)" ::: "memory");
    __builtin_amdgcn_sched_barrier(0);
    __builtin_amdgcn_s_barrier();
    // entering tile 0: outstanding = {BH(0)} = 2

    bf16x8 aL[2][2], aH[2][2], bL[2][2], bH[2][2];

    for (int t = 0; t < NT; ++t) {
        const int sel = t & 1;
        const bool pf = (t + 1 < NT);
        // ph0: read aL,bL(t) | issue BL(t+1), Af32(t+1)
        LDA2(aL, sel, 0); LDB2(bL, sel, 0);
        if (pf) {
            STAGE_B(sel ^ 1, 0, 0, t + 1); STAGE_B(sel ^ 1, 0, 1, t + 1);
            LOAD_A(t + 1);
        }
        __builtin_amdgcn_s_barrier();
        MM(aL, bL, 0, 0);
        __builtin_amdgcn_s_barrier();
        // ph1: read aH(t)
        LDA2(aH, sel, 1);
        __builtin_amdgcn_s_barrier();
        MM(aH, bL, 2, 0);
        if (pf) asm volatile("s_waitcnt vmcnt(6)" ::: "memory");   // BH(t) landed
        else    asm volatile("s_waitcnt vmcnt(0)" ::: "memory");
        __builtin_amdgcn_s_barrier();
        // ph2: read bH(t) | issue BH(t+1)
        LDB2(bH, sel, 1);
        if (pf) { STAGE_B(sel ^ 1, 1, 0, t + 1); STAGE_B(sel ^ 1, 1, 1, t + 1); }
        __builtin_amdgcn_s_barrier();
        MM(aH, bH, 2, 2);
        __builtin_amdgcn_s_barrier();
        // ph3: land A(t+1)+BL(t+1), write A(t+1) into buf[sel^1]
        if (pf) {
            asm volatile("s_waitcnt vmcnt(2)" ::: "memory");       // leaves only BH(t+1)
            __builtin_amdgcn_sched_barrier(0);                     // FENCE (rule #18)
            WRITE_A(sel ^ 1);
            asm volatile("s_waitcnt lgkmcnt(0)" ::: "memory");
            __builtin_amdgcn_sched_barrier(0);
        }
        __builtin_amdgcn_s_barrier();
        MM(aL, bH, 0, 2);
        __builtin_amdgcn_s_barrier();
    }
#undef STAGE_B

    const int nr0 = n0 & 1023;
    const float* bias = kreg ? biasv : biask;
    if (kreg == 0) {
#pragma unroll
        for (int b_ = 0; b_ < 4; b_++) {
            int n = nr0 + wcn * 16 + 64 * b_ + r16;
            float bs = bias[n];
#pragma unroll
            for (int a_ = 0; a_ < 4; a_++) {
                int mr = m0 + wr * 16 + 32 * a_ + g4 * 4;
#pragma unroll
                for (int r = 0; r < 4; r++)
                    Kb[(size_t)(mr + r) * 1024 + n] = f2b(acc[a_][b_][r] + bs);
            }
        }
    } else {
#pragma unroll
        for (int b_ = 0; b_ < 4; b_++) {
            int n = nr0 + wcn * 16 + 64 * b_ + r16;
            float bs = bias[n];
            int h = n >> 7, d = n & 127;
#pragma unroll
            for (int a_ = 0; a_ < 4; a_++) {
                int mr = m0 + wr * 16 + 32 * a_ + g4 * 4;
                int bb = mr >> 10, s_ = mr & 1023;
                ushort4 o;
                o.x = f2b(acc[a_][b_][0] + bs);
                o.y = f2b(acc[a_][b_][1] + bs);
                o.z = f2b(acc[a_][b_][2] + bs);
                o.w = f2b(acc[a_][b_][3] + bs);
                *(ushort4*)&Vt[((size_t)(bb * 8 + h) * 128 + d) * 1024 + s_] = o;
            }
        }
    }
}

// ---------------- flash attention v8 (unchanged) ----------------
__global__ __launch_bounds__(256, 2) void attn_kernel(const ushort* __restrict__ Q,
                                                      const ushort* __restrict__ Kt,
                                                      const ushort* __restrict__ Vt,
                                                      const int* __restrict__ mask,
                                                      ushort* __restrict__ xq) {
    __shared__ ushort Ks[2][8192];
    __shared__ ushort Vs[2][8192];

    const int tid = threadIdx.x;
    const int l = tid & 63, wid = tid >> 6;
    const int ql = l & 31, hi = l >> 5;
    const int id = blockIdx.x;
    const int bh = ((id >> 6) << 3) | (id & 7);
    const int qb = (id >> 3) & 7;
    const int b = bh >> 3, h = bh & 7;
    const int q0 = qb * 128 + wid * 32;

    bf16x8 qf[8];
    const ushort* Qrow = Q + (size_t)(b * 1024 + q0 + ql) * 1024 + h * 128 + hi * 8;
#pragma unroll
    for (int ks = 0; ks < 8; ks++) qf[ks] = *(const bf16x8*)(Qrow + ks * 16);

    const ushort* Kg = Kt + ((size_t)b * 1024) * 1024 + h * 128;
    const ushort* Vg = Vt + (size_t)(b * 8 + h) * 128 * 1024;
    const int* mptr = mask + b * 1024;

    f32x16 xacc[4];
#pragma unroll
    for (int i = 0; i < 4; i++)
#pragma unroll
        for (int r = 0; r < 16; r++) xacc[i][r] = 0.f;
    float mrow = -INFINITY, lrow = 0.f, sclp = 0.f;
    bool resc = true;
    bf16x8 pa[4];

    auto STAGE_K = [&](int sel, int t) {
        const int kv0 = t * 64;
#pragma unroll
        for (int it = 0; it < 4; ++it) {
            int ob = it * 4096 + wid * 1024;
            int o = ob + l * 16;
            int row = o >> 8;
            int sc = (o & 255) ^ ((row & 7) << 4);
            const ushort* src = Kg + (size_t)(kv0 + row) * 1024 + (sc >> 1);
            __builtin_amdgcn_global_load_lds((const __attribute__((address_space(1))) void*)src,
                (__attribute__((address_space(3))) void*)((char*)&Ks[sel][0] + ob), 16, 0, 0);
        }
    };
    auto STAGE_V = [&](int sel, int t) {
        const int kv0 = t * 64;
#pragma unroll
        for (int it = 0; it < 4; ++it) {
            int ob = it * 4096 + wid * 1024;
            int o = ob + l * 16;
            int d = o >> 7;
            int sc = (o & 127) ^ ((d & 7) << 4);
            const ushort* src = Vg + (size_t)d * 1024 + kv0 + (sc >> 1);
            __builtin_amdgcn_global_load_lds((const __attribute__((address_space(1))) void*)src,
                (__attribute__((address_space(3))) void*)((char*)&Vs[sel][0] + ob), 16, 0, 0);
        }
    };

    auto QK = [&](f32x16 (&s)[2], int sel, unsigned long long wt) {
        const char* Kb_ = (const char*)&Ks[sel][0];
#pragma unroll
        for (int sub = 0; sub < 2; sub++) {
            f32x16 sa, sb;
#pragma unroll
            for (int r = 0; r < 16; r++) { sa[r] = 0.f; sb[r] = 0.f; }
            const int rowk = sub * 32 + ql;
            const char* kr = Kb_ + rowk * 256;
            const int sw = (rowk & 7) << 4;
            __builtin_amdgcn_s_setprio(1);
#pragma unroll
            for (int ks = 0; ks < 4; ks++) {
                bf16x8 k0 = *(const bf16x8*)(kr + (((2 * ks) * 32 + hi * 16) ^ sw));
                bf16x8 k1 = *(const bf16x8*)(kr + (((2 * ks + 1) * 32 + hi * 16) ^ sw));
                sa = __builtin_amdgcn_mfma_f32_32x32x16_bf16(k0, qf[2 * ks], sa, 0, 0, 0);
                sb = __builtin_amdgcn_mfma_f32_32x32x16_bf16(k1, qf[2 * ks + 1], sb, 0, 0, 0);
            }
            __builtin_amdgcn_s_setprio(0);
#pragma unroll
            for (int r = 0; r < 16; r++) sa[r] += sb[r];
#pragma unroll
            for (int q2 = 0; q2 < 4; q2++) {
                uint nib = (uint)(wt >> (8 * q2 + 4 * hi + 32 * sub)) & 15u;
#pragma unroll
                for (int r = 0; r < 4; r++)
                    if (!((nib >> r) & 1u)) sa[4 * q2 + r] = -1e9f;
            }
            s[sub] = sa;
        }
    };
    auto PV = [&](int sel) {
        const char* Vb_ = (const char*)&Vs[sel][0];
        if (resc) {
#pragma unroll
            for (int df = 0; df < 4; df++)
#pragma unroll
                for (int r = 0; r < 16; r++) xacc[df][r] *= sclp;
        }
        __builtin_amdgcn_s_setprio(1);
#pragma unroll
        for (int ks2 = 0; ks2 < 4; ks2++) {
#pragma unroll
            for (int df = 0; df < 4; df++) {
                const int d = df * 32 + ql;
                bf16x8 vfr = *(const bf16x8*)(Vb_ + d * 128 + ((ks2 * 32 + hi * 16) ^ ((d & 7) << 4)));
                xacc[df] = __builtin_amdgcn_mfma_f32_32x32x16_bf16(vfr, pa[ks2], xacc[df], 0, 0, 0);
            }
        }
        __builtin_amdgcn_s_setprio(0);
    };
    auto SOFTMAX = [&](f32x16 (&s)[2]) {
        float v[16];
#pragma unroll
        for (int r = 0; r < 16; r++) v[r] = fmaxf(s[0][r], s[1][r]);
#pragma unroll
        for (int st = 8; st; st >>= 1)
#pragma unroll
            for (int i = 0; i < 8; i++)
                if (i < st) v[i] = fmaxf(v[i], v[i + st]);
        float pmax = fmaxf(v[0], __shfl_xor(v[0], 32));
        if (!__all(pmax - mrow <= 8.f)) {
            float mn = fmaxf(mrow, pmax);
            sclp = __expf(mrow - mn);
            mrow = mn;
            resc = true;
        } else {
            resc = false;
        }
        float rsum = 0.f;
#pragma unroll
        for (int res = 0; res < 2; res++)
#pragma unroll
            for (int r = 0; r < 16; r++) {
                float p = __expf(s[res][r] - mrow);
                s[res][r] = p;
                rsum += p;
            }
        rsum += __shfl_xor(rsum, 32);
        lrow = (resc ? lrow * sclp : lrow) + rsum;
#pragma unroll
        for (int sub = 0; sub < 2; sub++)
#pragma unroll
            for (int g = 0; g < 2; g++) {
                const int b0 = g * 8;
                uint lo01 = cvtpk(s[sub][b0 + 0], s[sub][b0 + 1]);
                uint lo23 = cvtpk(s[sub][b0 + 2], s[sub][b0 + 3]);
                uint hi01 = cvtpk(s[sub][b0 + 4], s[sub][b0 + 5]);
                uint hi23 = cvtpk(s[sub][b0 + 6], s[sub][b0 + 7]);
                i32x2 r02 = __builtin_amdgcn_permlane32_swap((int)lo01, (int)hi01, false, false);
                i32x2 r13 = __builtin_amdgcn_permlane32_swap((int)lo23, (int)hi23, false, false);
                union { bf16x8 vv; uint u[4]; } pk;
                pk.u[0] = (uint)r02.x;
                pk.u[1] = (uint)r13.x;
                pk.u[2] = (uint)r02.y;
                pk.u[3] = (uint)r13.y;
                pa[sub * 2 + g] = pk.vv;
            }
    };

    STAGE_K(0, 0);
    int mv = mptr[l];
    asm volatile("s_waitcnt vmcnt(0)" ::: "memory");
    __syncthreads();
    STAGE_K(1, 1);
    STAGE_V(0, 0);
    unsigned long long wt = __ballot(mv != 0);
    mv = mptr[64 + l];
    f32x16 s[2];
    QK(s, 0, wt);
    SOFTMAX(s);
    int kc = 1, vc = 0;

    for (int u = 1; u < 16; ++u) {
        wt = __ballot(mv != 0);
        asm volatile("s_waitcnt vmcnt(0)" ::: "memory");
        __syncthreads();
        if (u < 15) STAGE_K(kc ^ 1, u + 1);
        STAGE_V(vc ^ 1, u);
        if (u < 15) mv = mptr[(u + 1) * 64 + l];

        QK(s, kc, wt);
        PV(vc);
        SOFTMAX(s);

        kc ^= 1; vc ^= 1;
    }

    asm volatile("s_waitcnt vmcnt(0)" ::: "memory");
    __syncthreads();
    PV(vc);

    const float inv = 1.f / lrow;
    const size_t orow = (size_t)(b * 1024 + q0 + ql) * 2048 + h * 128;
#pragma unroll
    for (int df = 0; df < 4; df++) {
#pragma unroll
        for (int q2 = 0; q2 < 4; q2++) {
            ushort4 o;
            o.x = f2b(xacc[df][4 * q2 + 0] * inv);
            o.y = f2b(xacc[df][4 * q2 + 1] * inv);
            o.z = f2b(xacc[df][4 * q2 + 2] * inv);
            o.w = f2b(xacc[df][4 * q2 + 3] * inv);
            *(ushort4*)&xq[orow + df * 32 + 8 * q2 + 4 * hi] = o;
        }
    }
}

extern "C" void kernel_launch(void* const* d_in, const int* in_sizes, int n_in,
                              void* d_out, int out_size, void* d_ws, size_t ws_size,
                              hipStream_t stream) {
    const float* query = (const float*)d_in[0];
    const float* value = (const float*)d_in[1];
    const float* key   = (const float*)d_in[2];
    const int*   mask  = (const int*)d_in[3];
    const float* ln_a  = (const float*)d_in[4];
    const float* ln_b  = (const float*)d_in[5];
    const float* wq    = (const float*)d_in[6];
    const float* bq    = (const float*)d_in[7];
    const float* wk    = (const float*)d_in[8];
    const float* bk    = (const float*)d_in[9];
    const float* wv    = (const float*)d_in[10];
    const float* bv    = (const float*)d_in[11];
    const float* waoa  = (const float*)d_in[12];
    const float* baoa  = (const float*)d_in[13];
    float* out = (float*)d_out;

    char* w8 = (char*)d_ws;
    ushort* xq   = (ushort*)(w8);                 // 8192x2048 bf16 ([x | q_ln])
    ushort* Qb   = (ushort*)(w8 + 33554432);      // 8192x1024 bf16
    ushort* Kb   = (ushort*)(w8 + 50331648);      // 8192x1024 bf16
    ushort* Vt   = (ushort*)(w8 + 67108864);      // (B,H,128,S) bf16
    ushort* wqb  = (ushort*)(w8 + 117440512);     // 3x 1024x1024 bf16 contiguous (wq|wk|wv)
    ushort* wab  = (ushort*)(w8 + 123731968);     // 2048x2048 bf16 (PERMUTED)

    cast_all<<<7168, 256, 0, stream>>>(wq, wk, wv, waoa, wqb, wab);
    ln_kernel<<<8192, 256, 0, stream>>>(query, ln_a, ln_b, xq);

    const float qscale = 0.08838834764831845f; // 1/sqrt(128)

    // Q projection: M=8192, N=1024, K=1024 -> 256 blocks = 1 round
    gemm7q<<<256, 512, 0, stream>>>(xq + 1024, 2048, wqb, 1024, bq, Qb, qscale);
    // K/V projections: A read directly from f32 key/value -> 512 blocks = 2 rounds
    gemm7kv<<<512, 512, 0, stream>>>(key, value, wqb + 1048576, 1024, bk, bv, Kb, Vt);

    attn_kernel<<<512, 256, 0, stream>>>(Qb, Kb, Vt, mask, xq);

    gemm6<1><<<256, 512, 0, stream>>>(xq, 2048, wab, 2048, baoa, out, 2048, 8);
}